// Round 3
// baseline (37.788 us; speedup 1.0000x reference)
//
#include <hip/hip_runtime.h>
#include <hip/hip_bf16.h>
#include <math.h>

#define KN 8192
#define DEG 32
#define EE (KN*DEG)
#define WPB 4

// VAR = float32(10^(-19.9) * 5000000 / 10)
#define VAR_F 6.294627058970831e-15f

typedef __attribute__((ext_vector_type(8)))  short bf16x8;
typedef __attribute__((ext_vector_type(16))) float f32x16;

static __device__ __forceinline__ short bf_hi(float f) {
    __hip_bfloat16 h = __float2bfloat16(f);
    return __builtin_bit_cast(short, h);
}
static __device__ __forceinline__ float bf_f(short s) {
    __hip_bfloat16 h = __builtin_bit_cast(__hip_bfloat16, s);
    return __bfloat162float(h);
}

// Kernel 1: fused 3x conv + head. 4 waves/block, one node per wave.
// All weights except Wm2 staged to LDS with float4 loads; Wm2 loaded
// strided (naturally coalesced in the MFMA B-fragment layout).
// msg GEMM (32e x 32i x 32j) via mfma_f32_32x32x16_bf16, 3-term hi/lo split.
__global__ __launch_bounds__(256, 4) void mpnn_fused(
    const float* __restrict__ x,
    const float* __restrict__ edge_attr,
    const float* __restrict__ Wm1, const float* __restrict__ bm1,
    const float* __restrict__ Wm2, const float* __restrict__ bm2,
    const float* __restrict__ Wu1, const float* __restrict__ bu1,
    const float* __restrict__ Wu2, const float* __restrict__ bu2,
    const float* __restrict__ Wh1, const float* __restrict__ bh1,
    const float* __restrict__ Wh2, const float* __restrict__ bh2,
    float* __restrict__ p_out)
{
    __shared__ __align__(16) float wlds[WPB][1360];
    __shared__ __align__(16) float c_lds[WPB][32];
    __shared__ float xt[WPB][44];    // [0..8]=x, [9..40]=aggr
    __shared__ float ubuf[WPB][16];

    const int w    = threadIdx.x >> 6;
    const int lane = threadIdx.x & 63;
    const int col  = lane & 31;
    const int g    = lane >> 5;
    const int k    = blockIdx.x * WPB + w;
    float* WL = wlds[w];

    enum { O_WM1 = 0,    O_WU1 = 320,  O_WH1 = 976,  O_WU2 = 1104,
           O_BM1 = 1232, O_BM2 = 1264, O_BU1 = 1296, O_BU2 = 1312,
           O_BH1 = 1320, O_WH2 = 1336, O_BH2 = 1352 };

    // ---- cooperative LDS staging (wide loads) ----
    {
        const float4* s4 = (const float4*)(Wm1 + (size_t)k*320);
        float4* d4 = (float4*)(WL + O_WM1);                 // 320 = 80 f4
        d4[lane] = s4[lane];
        if (lane < 16) d4[64+lane] = s4[64+lane];

        s4 = (const float4*)(Wu1 + (size_t)k*656);          // 656 = 164 f4
        d4 = (float4*)(WL + O_WU1);
        d4[lane]    = s4[lane];
        d4[64+lane] = s4[64+lane];
        if (lane < 36) d4[128+lane] = s4[128+lane];

        if (lane < 32)
            ((float4*)(WL + O_WH1))[lane]    = ((const float4*)(Wh1 + (size_t)k*128))[lane];
        else
            ((float4*)(WL + O_WU2))[lane-32] = ((const float4*)(Wu2 + (size_t)k*128))[lane-32];

        if      (lane <  8) ((float4*)(WL + O_BM1))[lane]    = ((const float4*)(bm1 + (size_t)k*32))[lane];
        else if (lane < 16) ((float4*)(WL + O_BM2))[lane- 8] = ((const float4*)(bm2 + (size_t)k*32))[lane-8];
        else if (lane < 20) ((float4*)(WL + O_BU1))[lane-16] = ((const float4*)(bu1 + (size_t)k*16))[lane-16];
        else if (lane < 22) ((float4*)(WL + O_BU2))[lane-20] = ((const float4*)(bu2 + (size_t)k*8 ))[lane-20];
        else if (lane < 26) ((float4*)(WL + O_BH1))[lane-22] = ((const float4*)(bh1 + (size_t)k*16))[lane-22];
        else if (lane < 30) ((float4*)(WL + O_WH2))[lane-26] = ((const float4*)(Wh2 + (size_t)k*16))[lane-26];
        else if (lane == 30) WL[O_BH2] = bh2[k];

        if (lane >= 40 && lane < 49) xt[w][lane-40] = x[(size_t)k*9 + lane - 40];
    }

    const float a_e = edge_attr[k*32 + col];    // edge e = col

    // B fragments: B[kk=s*16+g*8+i][col] = Wm2[j][col]  (coalesced 128B rows)
    bf16x8 Bhi[2], Blo[2];
    #pragma unroll
    for (int s = 0; s < 2; ++s) {
        #pragma unroll
        for (int i = 0; i < 8; ++i) {
            int j = s*16 + g*8 + i;
            float wv = Wm2[(size_t)k*1024 + j*32 + col];
            short h = bf_hi(wv);
            Bhi[s][i] = h;
            Blo[s][i] = bf_hi(wv - bf_f(h));
        }
    }

    __syncthreads();

    const float bm1_i = WL[O_BM1 + col];
    const float bm2_i = WL[O_BM2 + col];
    const int m  = lane & 15;
    const int dg = lane >> 4;       // 0..3
    const int o  = lane & 7;
    const int mg = lane >> 3;       // 0..7

    for (int it = 0; it < 3; ++it) {
        // c_j = bm1_j + sum_d x_d Wm1[d][j]  (lane computes j = col)
        float c = bm1_i;
        #pragma unroll
        for (int d = 0; d < 9; ++d) c = fmaf(xt[w][d], WL[O_WM1 + d*32 + col], c);
        if (g == 0) c_lds[w][col] = c;
        __syncthreads();

        // A fragments: A[e=col][kk=s*16+g*8+i] = relu(c_j + a_e*Wm1[9][j])
        const float4* cb = (const float4*)c_lds[w];
        float4 q0 = cb[g*2 + 0];
        float4 q1 = cb[g*2 + 1];
        float4 q2 = cb[4 + g*2 + 0];
        float4 q3 = cb[4 + g*2 + 1];
        float cv[16] = {q0.x,q0.y,q0.z,q0.w, q1.x,q1.y,q1.z,q1.w,
                        q2.x,q2.y,q2.z,q2.w, q3.x,q3.y,q3.z,q3.w};
        bf16x8 Ahi[2], Alo[2];
        #pragma unroll
        for (int s = 0; s < 2; ++s) {
            #pragma unroll
            for (int i = 0; i < 8; ++i) {
                int t = s*8 + i;
                float w9 = WL[O_WM1 + 288 + (s*16 + g*8 + i)];
                float hv = fmaxf(fmaf(a_e, w9, cv[t]), 0.f);
                short h = bf_hi(hv);
                Ahi[s][i] = h;
                Alo[s][i] = bf_hi(hv - bf_f(h));
            }
        }

        // msg GEMM: D[e][i] = sum_j h[e][j] Wm2[j][i]
        f32x16 acc;
        #pragma unroll
        for (int r = 0; r < 16; ++r) acc[r] = 0.f;
        #pragma unroll
        for (int s = 0; s < 2; ++s) {
            acc = __builtin_amdgcn_mfma_f32_32x32x16_bf16(Ahi[s], Bhi[s], acc, 0, 0, 0);
            acc = __builtin_amdgcn_mfma_f32_32x32x16_bf16(Ahi[s], Blo[s], acc, 0, 0, 0);
            acc = __builtin_amdgcn_mfma_f32_32x32x16_bf16(Alo[s], Bhi[s], acc, 0, 0, 0);
        }

        // aggr_i = sum_e relu(bm2_i + D[e][i])
        float ag = 0.f;
        #pragma unroll
        for (int r = 0; r < 16; ++r) ag += fmaxf(acc[r] + bm2_i, 0.f);
        ag += __shfl_xor(ag, 32);
        if (g == 0) xt[w][9 + col] = ag;
        __syncthreads();

        // u_m = relu(bu1_m + sum_{d<41} t_d Wu1[d][m])
        float up = 0.f;
        #pragma unroll
        for (int t = 0; t < 11; ++t) {
            int d = dg*11 + t;
            if (d < 41) up = fmaf(xt[w][d], WL[O_WU1 + d*16 + m], up);
        }
        up += __shfl_xor(up, 16);
        up += __shfl_xor(up, 32);
        float u = fmaxf(up + WL[O_BU1 + m], 0.f);
        if (lane < 16) ubuf[w][lane] = u;
        __syncthreads();

        // comb_o = relu(bu2_o + sum_m u_m Wu2[m][o])
        float cp = WL[O_WU2 + (mg*2+0)*8 + o] * ubuf[w][mg*2]
                 + WL[O_WU2 + (mg*2+1)*8 + o] * ubuf[w][mg*2+1];
        cp += __shfl_xor(cp, 8);
        cp += __shfl_xor(cp, 16);
        cp += __shfl_xor(cp, 32);
        float comb = fmaxf(cp + WL[O_BU2 + o], 0.f);
        if (lane < 8) xt[w][1 + lane] = comb;   // x_new = [x0, comb]
        __syncthreads();
    }

    // head
    float hp = 0.f;
    #pragma unroll
    for (int d = 0; d < 8; ++d) hp = fmaf(xt[w][1 + d], WL[O_WH1 + d*16 + m], hp);
    float hh = fmaxf(hp + WL[O_BH1 + m], 0.f);
    float pp = hh * WL[O_WH2 + m];
    pp += __shfl_xor(pp, 1);
    pp += __shfl_xor(pp, 2);
    pp += __shfl_xor(pp, 4);
    pp += __shfl_xor(pp, 8);
    float z = pp + WL[O_BH2];
    float p = 1.f / (1.f + expf(-z));
    if (lane == 0) p_out[k] = p;
}

// Kernel 2: interference + rate. 32 lanes per node.
__global__ __launch_bounds__(256) void mpnn_interf(
    const float* __restrict__ H,
    const int* __restrict__ edge_index,
    const float* __restrict__ p,
    float* __restrict__ out)
{
    const int t = blockIdx.x * 256 + threadIdx.x;
    const int s = t >> 5;
    const int e = t & 31;
    const int* dst = edge_index + EE;
    const int d = dst[s*DEG + e];
    float part = p[d] * H[(size_t)s*KN + d];
    part += __shfl_xor(part, 1);
    part += __shfl_xor(part, 2);
    part += __shfl_xor(part, 4);
    part += __shfl_xor(part, 8);
    part += __shfl_xor(part, 16);
    if (e == 0) {
        float interf = part + VAR_F;
        float valid  = p[s] * H[(size_t)s*KN + s];
        out[s] = -log1pf(valid / interf) * 1.4426950408889634f;
    }
}

extern "C" void kernel_launch(void* const* d_in, const int* in_sizes, int n_in,
                              void* d_out, int out_size, void* d_ws, size_t ws_size,
                              hipStream_t stream) {
    const float* x         = (const float*)d_in[0];
    const float* edge_attr = (const float*)d_in[1];
    const float* H         = (const float*)d_in[2];
    const int*   edge_idx  = (const int*)  d_in[3];
    const float* Wm1 = (const float*)d_in[4];
    const float* bm1 = (const float*)d_in[5];
    const float* Wm2 = (const float*)d_in[6];
    const float* bm2 = (const float*)d_in[7];
    const float* Wu1 = (const float*)d_in[8];
    const float* bu1 = (const float*)d_in[9];
    const float* Wu2 = (const float*)d_in[10];
    const float* bu2 = (const float*)d_in[11];
    const float* Wh1 = (const float*)d_in[12];
    const float* bh1 = (const float*)d_in[13];
    const float* Wh2 = (const float*)d_in[14];
    const float* bh2 = (const float*)d_in[15];
    float* out = (float*)d_out;
    float* p_ws = (float*)d_ws;   // KN floats

    mpnn_fused<<<KN/WPB, 256, 0, stream>>>(x, edge_attr, Wm1, bm1, Wm2, bm2,
                                           Wu1, bu1, Wu2, bu2, Wh1, bh1, Wh2, bh2,
                                           p_ws);
    mpnn_interf<<<(KN*DEG)/256, 256, 0, stream>>>(H, edge_idx, p_ws, out);
}

// Round 4
// 35.667 us; speedup vs baseline: 1.0595x; 1.0595x over previous
//
#include <hip/hip_runtime.h>
#include <hip/hip_bf16.h>
#include <math.h>

#define KN 8192
#define DEG 32
#define EE (KN*DEG)
#define WPB 4

// VAR = float32(10^(-19.9) * 5000000 / 10)
#define VAR_F 6.294627058970831e-15f

typedef __attribute__((ext_vector_type(8)))  short bf16x8;
typedef __attribute__((ext_vector_type(16))) float f32x16;

static __device__ __forceinline__ short bf_hi(float f) {
    __hip_bfloat16 h = __float2bfloat16(f);
    return __builtin_bit_cast(short, h);
}
static __device__ __forceinline__ float bf_f(short s) {
    __hip_bfloat16 h = __builtin_bit_cast(__hip_bfloat16, s);
    return __bfloat162float(h);
}

// Kernel 1: fused 3x conv + head. 4 independent waves/block, one node per wave.
// Weights staged global->LDS with float4 loads (few, wide, clustered VMEM),
// then read ONCE into registers (round-2 layout); compute is register-resident.
// All LDS is wave-private -> no __syncthreads anywhere (wave-lockstep ordering).
// msg GEMM (32e x 32i x 32j) via mfma_f32_32x32x16_bf16, 3-term hi/lo split.
__global__ __launch_bounds__(256, 4) void mpnn_fused(
    const float* __restrict__ x,
    const float* __restrict__ edge_attr,
    const float* __restrict__ Wm1, const float* __restrict__ bm1,
    const float* __restrict__ Wm2, const float* __restrict__ bm2,
    const float* __restrict__ Wu1, const float* __restrict__ bu1,
    const float* __restrict__ Wu2, const float* __restrict__ bu2,
    const float* __restrict__ Wh1, const float* __restrict__ bh1,
    const float* __restrict__ Wh2, const float* __restrict__ bh2,
    float* __restrict__ p_out)
{
    __shared__ __align__(16) float wlds[WPB][1360];
    __shared__ __align__(16) float c_lds[WPB][32];
    __shared__ float xt[WPB][44];    // [0..8]=x, [9..40]=aggr
    __shared__ float ubuf[WPB][16];

    const int w    = threadIdx.x >> 6;
    const int lane = threadIdx.x & 63;
    const int col  = lane & 31;
    const int g    = lane >> 5;
    const int k    = blockIdx.x * WPB + w;
    float* WL = wlds[w];

    enum { O_WM1 = 0,    O_WU1 = 320,  O_WH1 = 976,  O_WU2 = 1104,
           O_BM1 = 1232, O_BM2 = 1264, O_BU1 = 1296, O_BU2 = 1312,
           O_BH1 = 1320, O_WH2 = 1336, O_BH2 = 1352 };

    // ---- wave-private LDS staging (wide loads, no barrier needed) ----
    {
        const float4* s4 = (const float4*)(Wm1 + (size_t)k*320);
        float4* d4 = (float4*)(WL + O_WM1);                 // 320 = 80 f4
        d4[lane] = s4[lane];
        if (lane < 16) d4[64+lane] = s4[64+lane];

        s4 = (const float4*)(Wu1 + (size_t)k*656);          // 656 = 164 f4
        d4 = (float4*)(WL + O_WU1);
        d4[lane]    = s4[lane];
        d4[64+lane] = s4[64+lane];
        if (lane < 36) d4[128+lane] = s4[128+lane];

        if (lane < 32)
            ((float4*)(WL + O_WH1))[lane]    = ((const float4*)(Wh1 + (size_t)k*128))[lane];
        else
            ((float4*)(WL + O_WU2))[lane-32] = ((const float4*)(Wu2 + (size_t)k*128))[lane-32];

        if      (lane <  8) ((float4*)(WL + O_BM1))[lane]    = ((const float4*)(bm1 + (size_t)k*32))[lane];
        else if (lane < 16) ((float4*)(WL + O_BM2))[lane- 8] = ((const float4*)(bm2 + (size_t)k*32))[lane-8];
        else if (lane < 20) ((float4*)(WL + O_BU1))[lane-16] = ((const float4*)(bu1 + (size_t)k*16))[lane-16];
        else if (lane < 22) ((float4*)(WL + O_BU2))[lane-20] = ((const float4*)(bu2 + (size_t)k*8 ))[lane-20];
        else if (lane < 26) ((float4*)(WL + O_BH1))[lane-22] = ((const float4*)(bh1 + (size_t)k*16))[lane-22];
        else if (lane < 30) ((float4*)(WL + O_WH2))[lane-26] = ((const float4*)(Wh2 + (size_t)k*16))[lane-26];
        else if (lane == 30) WL[O_BH2] = bh2[k];

        if (lane >= 40 && lane < 49) xt[w][lane-40] = x[(size_t)k*9 + lane - 40];
    }

    const float a_e = edge_attr[k*32 + col];    // edge e = col

    // B fragments direct from global: B[kk=s*16+g*8+i][col] = Wm2[j][col]
    // (each load = 2 coalesced 128B rows; already in fragment layout)
    bf16x8 Bhi[2], Blo[2];
    #pragma unroll
    for (int s = 0; s < 2; ++s) {
        #pragma unroll
        for (int i = 0; i < 8; ++i) {
            int j = s*16 + g*8 + i;
            float wv = Wm2[(size_t)k*1024 + j*32 + col];
            short h = bf_hi(wv);
            Bhi[s][i] = h;
            Blo[s][i] = bf_hi(wv - bf_f(h));
        }
    }

    // ---- one-time LDS -> register transfer (round-2 register layout) ----
    float wm1[9];
    #pragma unroll
    for (int d = 0; d < 9; ++d) wm1[d] = WL[O_WM1 + d*32 + col];
    const float bm1_i = WL[O_BM1 + col];
    const float bm2_i = WL[O_BM2 + col];

    float w9v[16];
    {
        const float4* w9p = (const float4*)(WL + O_WM1 + 288);
        float4 a0 = w9p[g*2 + 0];
        float4 a1 = w9p[g*2 + 1];
        float4 a2 = w9p[4 + g*2 + 0];
        float4 a3 = w9p[4 + g*2 + 1];
        w9v[0]=a0.x; w9v[1]=a0.y; w9v[2]=a0.z; w9v[3]=a0.w;
        w9v[4]=a1.x; w9v[5]=a1.y; w9v[6]=a1.z; w9v[7]=a1.w;
        w9v[8]=a2.x; w9v[9]=a2.y; w9v[10]=a2.z; w9v[11]=a2.w;
        w9v[12]=a3.x; w9v[13]=a3.y; w9v[14]=a3.z; w9v[15]=a3.w;
    }

    const int m  = lane & 15;
    const int dg = lane >> 4;        // 0..3
    float wu1[11];
    #pragma unroll
    for (int t = 0; t < 11; ++t) {
        int d = dg*11 + t;
        float v = WL[O_WU1 + d*16 + m];   // d<=43 -> stays inside wave slice
        wu1[t] = (d < 41) ? v : 0.f;
    }
    const float bu1_m = WL[O_BU1 + m];

    const int o  = lane & 7;
    const int mg = lane >> 3;        // 0..7
    const float wu2a  = WL[O_WU2 + (mg*2+0)*8 + o];
    const float wu2b  = WL[O_WU2 + (mg*2+1)*8 + o];
    const float bu2_o = WL[O_BU2 + o];

    float wh1[8];
    #pragma unroll
    for (int d = 0; d < 8; ++d) wh1[d] = WL[O_WH1 + d*16 + m];
    const float bh1_m = WL[O_BH1 + m];
    const float wh2_m = WL[O_WH2 + m];
    const float bh2_k = WL[O_BH2];

    for (int it = 0; it < 3; ++it) {
        // c_j = bm1_j + sum_d x_d Wm1[d][j]  (lane computes j = col)
        float c = bm1_i;
        #pragma unroll
        for (int d = 0; d < 9; ++d) c = fmaf(xt[w][d], wm1[d], c);
        if (g == 0) c_lds[w][col] = c;

        // A fragments: A[e=col][kk=s*16+g*8+i] = relu(c_j + a_e*Wm1[9][j])
        const float4* cb = (const float4*)c_lds[w];
        float4 q0 = cb[g*2 + 0];
        float4 q1 = cb[g*2 + 1];
        float4 q2 = cb[4 + g*2 + 0];
        float4 q3 = cb[4 + g*2 + 1];
        float cv[16] = {q0.x,q0.y,q0.z,q0.w, q1.x,q1.y,q1.z,q1.w,
                        q2.x,q2.y,q2.z,q2.w, q3.x,q3.y,q3.z,q3.w};
        bf16x8 Ahi[2], Alo[2];
        #pragma unroll
        for (int s = 0; s < 2; ++s) {
            #pragma unroll
            for (int i = 0; i < 8; ++i) {
                int t = s*8 + i;
                float hv = fmaxf(fmaf(a_e, w9v[t], cv[t]), 0.f);
                short h = bf_hi(hv);
                Ahi[s][i] = h;
                Alo[s][i] = bf_hi(hv - bf_f(h));
            }
        }

        // msg GEMM: D[e][i] = sum_j h[e][j] Wm2[j][i]
        f32x16 acc;
        #pragma unroll
        for (int r = 0; r < 16; ++r) acc[r] = 0.f;
        #pragma unroll
        for (int s = 0; s < 2; ++s) {
            acc = __builtin_amdgcn_mfma_f32_32x32x16_bf16(Ahi[s], Bhi[s], acc, 0, 0, 0);
            acc = __builtin_amdgcn_mfma_f32_32x32x16_bf16(Ahi[s], Blo[s], acc, 0, 0, 0);
            acc = __builtin_amdgcn_mfma_f32_32x32x16_bf16(Alo[s], Bhi[s], acc, 0, 0, 0);
        }

        // aggr_i = sum_e relu(bm2_i + D[e][i])
        float ag = 0.f;
        #pragma unroll
        for (int r = 0; r < 16; ++r) ag += fmaxf(acc[r] + bm2_i, 0.f);
        ag += __shfl_xor(ag, 32);
        if (g == 0) xt[w][9 + col] = ag;

        // u_m = relu(bu1_m + sum_{d<41} t_d Wu1[d][m])
        float up = 0.f;
        #pragma unroll
        for (int t = 0; t < 11; ++t) {
            int d = dg*11 + t;
            if (d < 41) up = fmaf(xt[w][d], wu1[t], up);
        }
        up += __shfl_xor(up, 16);
        up += __shfl_xor(up, 32);
        float u = fmaxf(up + bu1_m, 0.f);
        if (lane < 16) ubuf[w][lane] = u;

        // comb_o = relu(bu2_o + sum_m u_m Wu2[m][o])
        float cp = wu2a * ubuf[w][mg*2] + wu2b * ubuf[w][mg*2+1];
        cp += __shfl_xor(cp, 8);
        cp += __shfl_xor(cp, 16);
        cp += __shfl_xor(cp, 32);
        float comb = fmaxf(cp + bu2_o, 0.f);
        if (lane < 8) xt[w][1 + lane] = comb;   // x_new = [x0, comb]
    }

    // head
    float hp = 0.f;
    #pragma unroll
    for (int d = 0; d < 8; ++d) hp = fmaf(xt[w][1 + d], wh1[d], hp);
    float hh = fmaxf(hp + bh1_m, 0.f);
    float pp = hh * wh2_m;
    pp += __shfl_xor(pp, 1);
    pp += __shfl_xor(pp, 2);
    pp += __shfl_xor(pp, 4);
    pp += __shfl_xor(pp, 8);
    float z = pp + bh2_k;
    float p = 1.f / (1.f + expf(-z));
    if (lane == 0) p_out[k] = p;
}

// Kernel 2: interference + rate. 32 lanes per node.
__global__ __launch_bounds__(256) void mpnn_interf(
    const float* __restrict__ H,
    const int* __restrict__ edge_index,
    const float* __restrict__ p,
    float* __restrict__ out)
{
    const int t = blockIdx.x * 256 + threadIdx.x;
    const int s = t >> 5;
    const int e = t & 31;
    const int* dst = edge_index + EE;
    const int d = dst[s*DEG + e];
    float part = p[d] * H[(size_t)s*KN + d];
    part += __shfl_xor(part, 1);
    part += __shfl_xor(part, 2);
    part += __shfl_xor(part, 4);
    part += __shfl_xor(part, 8);
    part += __shfl_xor(part, 16);
    if (e == 0) {
        float interf = part + VAR_F;
        float valid  = p[s] * H[(size_t)s*KN + s];
        out[s] = -log1pf(valid / interf) * 1.4426950408889634f;
    }
}

extern "C" void kernel_launch(void* const* d_in, const int* in_sizes, int n_in,
                              void* d_out, int out_size, void* d_ws, size_t ws_size,
                              hipStream_t stream) {
    const float* x         = (const float*)d_in[0];
    const float* edge_attr = (const float*)d_in[1];
    const float* H         = (const float*)d_in[2];
    const int*   edge_idx  = (const int*)  d_in[3];
    const float* Wm1 = (const float*)d_in[4];
    const float* bm1 = (const float*)d_in[5];
    const float* Wm2 = (const float*)d_in[6];
    const float* bm2 = (const float*)d_in[7];
    const float* Wu1 = (const float*)d_in[8];
    const float* bu1 = (const float*)d_in[9];
    const float* Wu2 = (const float*)d_in[10];
    const float* bu2 = (const float*)d_in[11];
    const float* Wh1 = (const float*)d_in[12];
    const float* bh1 = (const float*)d_in[13];
    const float* Wh2 = (const float*)d_in[14];
    const float* bh2 = (const float*)d_in[15];
    float* out = (float*)d_out;
    float* p_ws = (float*)d_ws;   // KN floats

    mpnn_fused<<<KN/WPB, 256, 0, stream>>>(x, edge_attr, Wm1, bm1, Wm2, bm2,
                                           Wu1, bu1, Wu2, bu2, Wh1, bh1, Wh2, bh2,
                                           p_ws);
    mpnn_interf<<<(KN*DEG)/256, 256, 0, stream>>>(H, edge_idx, p_ws, out);
}

// Round 5
// 31.983 us; speedup vs baseline: 1.1815x; 1.1152x over previous
//
#include <hip/hip_runtime.h>
#include <hip/hip_bf16.h>
#include <math.h>

#define KN 8192
#define DEG 32
#define EE (KN*DEG)

// VAR = float32(10^(-19.9) * 5000000 / 10)
#define VAR_F 6.294627058970831e-15f

typedef __attribute__((ext_vector_type(8)))  short bf16x8;
typedef __attribute__((ext_vector_type(16))) float f32x16;

static __device__ __forceinline__ short bf_hi(float f) {
    __hip_bfloat16 h = __float2bfloat16(f);
    return __builtin_bit_cast(short, h);
}
static __device__ __forceinline__ float bf_f(short s) {
    __hip_bfloat16 h = __builtin_bit_cast(__hip_bfloat16, s);
    return __bfloat162float(h);
}

// Kernel 1: fused 3x conv + head. ONE wave per block, one node per wave.
// All weights register-resident (loaded once, reused across the 3 convs).
// All fp32 loads issued before any conversion (clustered VMEM, max MLP).
// __launch_bounds__(64,4): VGPR<=128 -> 4 waves/SIMD to hide HBM latency.
// LDS is wave-private scratch (c broadcast, xt, ubuf) -> no barriers needed.
// msg GEMM (32e x 32i x 32j) via mfma_f32_32x32x16_bf16, 3-term hi/lo split.
__global__ __launch_bounds__(64, 4) void mpnn_fused(
    const float* __restrict__ x,
    const float* __restrict__ edge_attr,
    const float* __restrict__ Wm1, const float* __restrict__ bm1,
    const float* __restrict__ Wm2, const float* __restrict__ bm2,
    const float* __restrict__ Wu1, const float* __restrict__ bu1,
    const float* __restrict__ Wu2, const float* __restrict__ bu2,
    const float* __restrict__ Wh1, const float* __restrict__ bh1,
    const float* __restrict__ Wh2, const float* __restrict__ bh2,
    float* __restrict__ p_out)
{
    __shared__ __align__(16) float c_lds[32];
    __shared__ float xt[44];    // [0..8]=x, [9..40]=aggr
    __shared__ float ubuf[16];

    const int lane = threadIdx.x;
    const int col  = lane & 31;
    const int g    = lane >> 5;
    const int k    = blockIdx.x;

    const int m  = lane & 15;
    const int dg = lane >> 4;        // 0..3
    const int o  = lane & 7;
    const int mg = lane >> 3;        // 0..7

    // ================= all global fp32 loads first =================
    const float a_e = edge_attr[k*32 + col];          // edge e = col

    float wm1[9];
    #pragma unroll
    for (int d = 0; d < 9; ++d) wm1[d] = Wm1[(size_t)k*320 + d*32 + col];

    // Wm1 row 9 at this lane's 16 A-fragment j's: j = s*16 + g*8 + i
    // (two contiguous 8-float runs -> 4x float4, per-g-uniform addresses)
    float w9v[16];
    {
        const float* w9p = Wm1 + (size_t)k*320 + 288;
        float4 wa = *(const float4*)(w9p + g*8);
        float4 wb = *(const float4*)(w9p + g*8 + 4);
        float4 wc = *(const float4*)(w9p + 16 + g*8);
        float4 wd = *(const float4*)(w9p + 16 + g*8 + 4);
        w9v[0]=wa.x;  w9v[1]=wa.y;  w9v[2]=wa.z;  w9v[3]=wa.w;
        w9v[4]=wb.x;  w9v[5]=wb.y;  w9v[6]=wb.z;  w9v[7]=wb.w;
        w9v[8]=wc.x;  w9v[9]=wc.y;  w9v[10]=wc.z; w9v[11]=wc.w;
        w9v[12]=wd.x; w9v[13]=wd.y; w9v[14]=wd.z; w9v[15]=wd.w;
    }

    // Wm2 in B-fragment order (each instr = 2 coalesced 128B rows), fp32 now,
    // converted to bf16 hi/lo AFTER all loads are issued.
    float wm2f[16];
    #pragma unroll
    for (int s = 0; s < 2; ++s)
        #pragma unroll
        for (int i = 0; i < 8; ++i)
            wm2f[s*8+i] = Wm2[(size_t)k*1024 + (s*16 + g*8 + i)*32 + col];

    const float bm1_i = bm1[k*32 + col];
    const float bm2_i = bm2[k*32 + col];

    float wu1[11];
    #pragma unroll
    for (int t = 0; t < 11; ++t) {
        int d = dg*11 + t;
        wu1[t] = (d < 41) ? Wu1[(size_t)k*656 + d*16 + m] : 0.f;
    }
    const float bu1_m = bu1[k*16 + m];

    const float wu2a  = Wu2[(size_t)k*128 + (mg*2+0)*8 + o];
    const float wu2b  = Wu2[(size_t)k*128 + (mg*2+1)*8 + o];
    const float bu2_o = bu2[k*8 + o];

    float wh1[8];
    #pragma unroll
    for (int d = 0; d < 8; ++d) wh1[d] = Wh1[(size_t)k*128 + d*16 + m];
    const float bh1_m = bh1[k*16 + m];
    const float wh2_m = Wh2[k*16 + m];
    const float bh2_k = bh2[k];

    if (lane < 9) xt[lane] = x[(size_t)k*9 + lane];

    // ================= conversions (after loads) =================
    bf16x8 Bhi[2], Blo[2];
    #pragma unroll
    for (int s = 0; s < 2; ++s) {
        #pragma unroll
        for (int i = 0; i < 8; ++i) {
            float wv = wm2f[s*8+i];
            short h = bf_hi(wv);
            Bhi[s][i] = h;
            Blo[s][i] = bf_hi(wv - bf_f(h));
        }
    }

    // ================= 3x conv =================
    for (int it = 0; it < 3; ++it) {
        // c_j = bm1_j + sum_d x_d Wm1[d][j]  (lane computes j = col)
        float c = bm1_i;
        #pragma unroll
        for (int d = 0; d < 9; ++d) c = fmaf(xt[d], wm1[d], c);
        if (g == 0) c_lds[col] = c;

        // A fragments: A[e=col][kk=s*16+g*8+i] = relu(c_j + a_e*Wm1[9][j])
        const float4* cb = (const float4*)c_lds;
        float4 q0 = cb[g*2 + 0];
        float4 q1 = cb[g*2 + 1];
        float4 q2 = cb[4 + g*2 + 0];
        float4 q3 = cb[4 + g*2 + 1];
        float cv[16] = {q0.x,q0.y,q0.z,q0.w, q1.x,q1.y,q1.z,q1.w,
                        q2.x,q2.y,q2.z,q2.w, q3.x,q3.y,q3.z,q3.w};
        bf16x8 Ahi[2], Alo[2];
        #pragma unroll
        for (int s = 0; s < 2; ++s) {
            #pragma unroll
            for (int i = 0; i < 8; ++i) {
                int t = s*8 + i;
                float hv = fmaxf(fmaf(a_e, w9v[t], cv[t]), 0.f);
                short h = bf_hi(hv);
                Ahi[s][i] = h;
                Alo[s][i] = bf_hi(hv - bf_f(h));
            }
        }

        // msg GEMM: D[e][i] = sum_j h[e][j] Wm2[j][i]
        f32x16 acc;
        #pragma unroll
        for (int r = 0; r < 16; ++r) acc[r] = 0.f;
        #pragma unroll
        for (int s = 0; s < 2; ++s) {
            acc = __builtin_amdgcn_mfma_f32_32x32x16_bf16(Ahi[s], Bhi[s], acc, 0, 0, 0);
            acc = __builtin_amdgcn_mfma_f32_32x32x16_bf16(Ahi[s], Blo[s], acc, 0, 0, 0);
            acc = __builtin_amdgcn_mfma_f32_32x32x16_bf16(Alo[s], Bhi[s], acc, 0, 0, 0);
        }

        // aggr_i = sum_e relu(bm2_i + D[e][i]); lane holds col i, 16 rows
        float ag = 0.f;
        #pragma unroll
        for (int r = 0; r < 16; ++r) ag += fmaxf(acc[r] + bm2_i, 0.f);
        ag += __shfl_xor(ag, 32);
        if (g == 0) xt[9 + col] = ag;

        // u_m = relu(bu1_m + sum_{d<41} t_d Wu1[d][m]); t = [x(9), aggr(32)]
        float up = 0.f;
        #pragma unroll
        for (int t = 0; t < 11; ++t) {
            int d = dg*11 + t;
            if (d < 41) up = fmaf(xt[d], wu1[t], up);
        }
        up += __shfl_xor(up, 16);
        up += __shfl_xor(up, 32);
        float u = fmaxf(up + bu1_m, 0.f);
        if (lane < 16) ubuf[lane] = u;

        // comb_o = relu(bu2_o + sum_m u_m Wu2[m][o])
        float cp = wu2a * ubuf[mg*2] + wu2b * ubuf[mg*2 + 1];
        cp += __shfl_xor(cp, 8);
        cp += __shfl_xor(cp, 16);
        cp += __shfl_xor(cp, 32);
        float comb = fmaxf(cp + bu2_o, 0.f);
        if (lane < 8) xt[1 + lane] = comb;   // x_new = [x0, comb]
    }

    // ================= head =================
    float hp = 0.f;
    #pragma unroll
    for (int d = 0; d < 8; ++d) hp = fmaf(xt[1 + d], wh1[d], hp);
    float hh = fmaxf(hp + bh1_m, 0.f);
    float pp = hh * wh2_m;
    pp += __shfl_xor(pp, 1);
    pp += __shfl_xor(pp, 2);
    pp += __shfl_xor(pp, 4);
    pp += __shfl_xor(pp, 8);
    float z = pp + bh2_k;
    float p = 1.f / (1.f + expf(-z));
    if (lane == 0) p_out[k] = p;
}

// Kernel 2: interference + rate. 32 lanes per node.
__global__ __launch_bounds__(256) void mpnn_interf(
    const float* __restrict__ H,
    const int* __restrict__ edge_index,
    const float* __restrict__ p,
    float* __restrict__ out)
{
    const int t = blockIdx.x * 256 + threadIdx.x;
    const int s = t >> 5;
    const int e = t & 31;
    const int* dst = edge_index + EE;
    const int d = dst[s*DEG + e];
    float part = p[d] * H[(size_t)s*KN + d];
    part += __shfl_xor(part, 1);
    part += __shfl_xor(part, 2);
    part += __shfl_xor(part, 4);
    part += __shfl_xor(part, 8);
    part += __shfl_xor(part, 16);
    if (e == 0) {
        float interf = part + VAR_F;
        float valid  = p[s] * H[(size_t)s*KN + s];
        out[s] = -log1pf(valid / interf) * 1.4426950408889634f;
    }
}

extern "C" void kernel_launch(void* const* d_in, const int* in_sizes, int n_in,
                              void* d_out, int out_size, void* d_ws, size_t ws_size,
                              hipStream_t stream) {
    const float* x         = (const float*)d_in[0];
    const float* edge_attr = (const float*)d_in[1];
    const float* H         = (const float*)d_in[2];
    const int*   edge_idx  = (const int*)  d_in[3];
    const float* Wm1 = (const float*)d_in[4];
    const float* bm1 = (const float*)d_in[5];
    const float* Wm2 = (const float*)d_in[6];
    const float* bm2 = (const float*)d_in[7];
    const float* Wu1 = (const float*)d_in[8];
    const float* bu1 = (const float*)d_in[9];
    const float* Wu2 = (const float*)d_in[10];
    const float* bu2 = (const float*)d_in[11];
    const float* Wh1 = (const float*)d_in[12];
    const float* bh1 = (const float*)d_in[13];
    const float* Wh2 = (const float*)d_in[14];
    const float* bh2 = (const float*)d_in[15];
    float* out = (float*)d_out;
    float* p_ws = (float*)d_ws;   // KN floats

    mpnn_fused<<<KN, 64, 0, stream>>>(x, edge_attr, Wm1, bm1, Wm2, bm2,
                                      Wu1, bu1, Wu2, bu2, Wh1, bh1, Wh2, bh2,
                                      p_ws);
    mpnn_interf<<<(KN*DEG)/256, 256, 0, stream>>>(H, edge_idx, p_ws, out);
}

// Round 6
// 30.969 us; speedup vs baseline: 1.2202x; 1.0328x over previous
//
#include <hip/hip_runtime.h>
#include <hip/hip_bf16.h>
#include <math.h>

#define KN 8192
#define DEG 32
#define EE (KN*DEG)

// VAR = float32(10^(-19.9) * 5000000 / 10)
#define VAR_F 6.294627058970831e-15f

typedef __attribute__((ext_vector_type(8)))  short bf16x8;
typedef __attribute__((ext_vector_type(16))) float f32x16;

static __device__ __forceinline__ short bf_hi(float f) {
    __hip_bfloat16 h = __float2bfloat16(f);
    return __builtin_bit_cast(short, h);
}
static __device__ __forceinline__ float bf_f(short s) {
    __hip_bfloat16 h = __builtin_bit_cast(__hip_bfloat16, s);
    return __bfloat162float(h);
}

// Kernel 1: fused 3x conv + head + H-row gather. ONE wave per block/node.
// The H[s,dst] gather is p-independent, so it's overlapped with the weight
// stream here instead of serializing in a latency-bound second kernel.
// Weights register-resident; msg GEMM via mfma_f32_32x32x16_bf16 (3-term
// hi/lo split for ~fp32 precision). Wave-private LDS only -> no barriers.
__global__ __launch_bounds__(64, 4) void mpnn_fused(
    const float* __restrict__ x,
    const float* __restrict__ edge_attr,
    const float* __restrict__ H,
    const int* __restrict__ edge_index,
    const float* __restrict__ Wm1, const float* __restrict__ bm1,
    const float* __restrict__ Wm2, const float* __restrict__ bm2,
    const float* __restrict__ Wu1, const float* __restrict__ bu1,
    const float* __restrict__ Wu2, const float* __restrict__ bu2,
    const float* __restrict__ Wh1, const float* __restrict__ bh1,
    const float* __restrict__ Wh2, const float* __restrict__ bh2,
    float* __restrict__ p_ws, float* __restrict__ valid_ws,
    float* __restrict__ hv_ws)
{
    __shared__ __align__(16) float c_lds[32];
    __shared__ float xt[44];    // [0..8]=x, [9..40]=aggr
    __shared__ float ubuf[16];

    const int lane = threadIdx.x;
    const int col  = lane & 31;
    const int g    = lane >> 5;
    const int k    = blockIdx.x;

    const int m  = lane & 15;
    const int dg = lane >> 4;        // 0..3
    const int o  = lane & 7;
    const int mg = lane >> 3;        // 0..7

    // ---- H-row gather first (longest dependent chain: dst -> H line) ----
    const int* dst = edge_index + EE;
    const int dv = dst[k*DEG + col];
    const float Hv    = H[(size_t)k*KN + dv];       // random 4B within row
    const float Hdiag = H[(size_t)k*KN + k];        // uniform -> 1 line

    // ================= all global fp32 weight loads =================
    const float a_e = edge_attr[k*32 + col];          // edge e = col

    float wm1[9];
    #pragma unroll
    for (int d = 0; d < 9; ++d) wm1[d] = Wm1[(size_t)k*320 + d*32 + col];

    // Wm1 row 9 at this lane's 16 A-fragment j's: j = s*16 + g*8 + i
    float w9v[16];
    {
        const float* w9p = Wm1 + (size_t)k*320 + 288;
        float4 wa = *(const float4*)(w9p + g*8);
        float4 wb = *(const float4*)(w9p + g*8 + 4);
        float4 wc = *(const float4*)(w9p + 16 + g*8);
        float4 wd = *(const float4*)(w9p + 16 + g*8 + 4);
        w9v[0]=wa.x;  w9v[1]=wa.y;  w9v[2]=wa.z;  w9v[3]=wa.w;
        w9v[4]=wb.x;  w9v[5]=wb.y;  w9v[6]=wb.z;  w9v[7]=wb.w;
        w9v[8]=wc.x;  w9v[9]=wc.y;  w9v[10]=wc.z; w9v[11]=wc.w;
        w9v[12]=wd.x; w9v[13]=wd.y; w9v[14]=wd.z; w9v[15]=wd.w;
    }

    // Wm2 in B-fragment order (2 coalesced 128B rows per instr), fp32 first.
    float wm2f[16];
    #pragma unroll
    for (int s = 0; s < 2; ++s)
        #pragma unroll
        for (int i = 0; i < 8; ++i)
            wm2f[s*8+i] = Wm2[(size_t)k*1024 + (s*16 + g*8 + i)*32 + col];

    const float bm1_i = bm1[k*32 + col];
    const float bm2_i = bm2[k*32 + col];

    float wu1[11];
    #pragma unroll
    for (int t = 0; t < 11; ++t) {
        int d = dg*11 + t;
        wu1[t] = (d < 41) ? Wu1[(size_t)k*656 + d*16 + m] : 0.f;
    }
    const float bu1_m = bu1[k*16 + m];

    const float wu2a  = Wu2[(size_t)k*128 + (mg*2+0)*8 + o];
    const float wu2b  = Wu2[(size_t)k*128 + (mg*2+1)*8 + o];
    const float bu2_o = bu2[k*8 + o];

    float wh1[8];
    #pragma unroll
    for (int d = 0; d < 8; ++d) wh1[d] = Wh1[(size_t)k*128 + d*16 + m];
    const float bh1_m = bh1[k*16 + m];
    const float wh2_m = Wh2[k*16 + m];
    const float bh2_k = bh2[k];

    if (lane < 9) xt[lane] = x[(size_t)k*9 + lane];

    // stash gathered H values (p-independent part of interference)
    if (g == 0) hv_ws[k*DEG + col] = Hv;

    // ================= conversions (after loads issued) =================
    bf16x8 Bhi[2], Blo[2];
    #pragma unroll
    for (int s = 0; s < 2; ++s) {
        #pragma unroll
        for (int i = 0; i < 8; ++i) {
            float wv = wm2f[s*8+i];
            short h = bf_hi(wv);
            Bhi[s][i] = h;
            Blo[s][i] = bf_hi(wv - bf_f(h));
        }
    }

    // ================= 3x conv =================
    for (int it = 0; it < 3; ++it) {
        // c_j = bm1_j + sum_d x_d Wm1[d][j]  (lane computes j = col)
        float c = bm1_i;
        #pragma unroll
        for (int d = 0; d < 9; ++d) c = fmaf(xt[d], wm1[d], c);
        if (g == 0) c_lds[col] = c;

        // A fragments: A[e=col][kk=s*16+g*8+i] = relu(c_j + a_e*Wm1[9][j])
        const float4* cb = (const float4*)c_lds;
        float4 q0 = cb[g*2 + 0];
        float4 q1 = cb[g*2 + 1];
        float4 q2 = cb[4 + g*2 + 0];
        float4 q3 = cb[4 + g*2 + 1];
        float cv[16] = {q0.x,q0.y,q0.z,q0.w, q1.x,q1.y,q1.z,q1.w,
                        q2.x,q2.y,q2.z,q2.w, q3.x,q3.y,q3.z,q3.w};
        bf16x8 Ahi[2], Alo[2];
        #pragma unroll
        for (int s = 0; s < 2; ++s) {
            #pragma unroll
            for (int i = 0; i < 8; ++i) {
                int t = s*8 + i;
                float hv = fmaxf(fmaf(a_e, w9v[t], cv[t]), 0.f);
                short h = bf_hi(hv);
                Ahi[s][i] = h;
                Alo[s][i] = bf_hi(hv - bf_f(h));
            }
        }

        // msg GEMM: D[e][i] = sum_j h[e][j] Wm2[j][i]
        f32x16 acc;
        #pragma unroll
        for (int r = 0; r < 16; ++r) acc[r] = 0.f;
        #pragma unroll
        for (int s = 0; s < 2; ++s) {
            acc = __builtin_amdgcn_mfma_f32_32x32x16_bf16(Ahi[s], Bhi[s], acc, 0, 0, 0);
            acc = __builtin_amdgcn_mfma_f32_32x32x16_bf16(Ahi[s], Blo[s], acc, 0, 0, 0);
            acc = __builtin_amdgcn_mfma_f32_32x32x16_bf16(Alo[s], Bhi[s], acc, 0, 0, 0);
        }

        // aggr_i = sum_e relu(bm2_i + D[e][i]); lane holds col i, 16 rows
        float ag = 0.f;
        #pragma unroll
        for (int r = 0; r < 16; ++r) ag += fmaxf(acc[r] + bm2_i, 0.f);
        ag += __shfl_xor(ag, 32);
        if (g == 0) xt[9 + col] = ag;

        // u_m = relu(bu1_m + sum_{d<41} t_d Wu1[d][m]); t = [x(9), aggr(32)]
        float up = 0.f;
        #pragma unroll
        for (int t = 0; t < 11; ++t) {
            int d = dg*11 + t;
            if (d < 41) up = fmaf(xt[d], wu1[t], up);
        }
        up += __shfl_xor(up, 16);
        up += __shfl_xor(up, 32);
        float u = fmaxf(up + bu1_m, 0.f);
        if (lane < 16) ubuf[lane] = u;

        // comb_o = relu(bu2_o + sum_m u_m Wu2[m][o])
        float cp = wu2a * ubuf[mg*2] + wu2b * ubuf[mg*2 + 1];
        cp += __shfl_xor(cp, 8);
        cp += __shfl_xor(cp, 16);
        cp += __shfl_xor(cp, 32);
        float comb = fmaxf(cp + bu2_o, 0.f);
        if (lane < 8) xt[1 + lane] = comb;   // x_new = [x0, comb]
    }

    // ================= head =================
    float hp = 0.f;
    #pragma unroll
    for (int d = 0; d < 8; ++d) hp = fmaf(xt[1 + d], wh1[d], hp);
    float hh = fmaxf(hp + bh1_m, 0.f);
    float pp = hh * wh2_m;
    pp += __shfl_xor(pp, 1);
    pp += __shfl_xor(pp, 2);
    pp += __shfl_xor(pp, 4);
    pp += __shfl_xor(pp, 8);
    float z = pp + bh2_k;
    float p = 1.f / (1.f + expf(-z));
    if (lane == 0) {
        p_ws[k] = p;
        valid_ws[k] = p * Hdiag;
    }
}

// Kernel 2b: interference reduce from compact buffers. 32 lanes per node.
// Streams hv_ws (1 MB) + dst (1 MB); p gather is a 32 KB L2-resident table.
__global__ __launch_bounds__(256) void mpnn_interf(
    const int* __restrict__ edge_index,
    const float* __restrict__ p_ws,
    const float* __restrict__ valid_ws,
    const float* __restrict__ hv_ws,
    float* __restrict__ out)
{
    const int t = blockIdx.x * 256 + threadIdx.x;
    const int s = t >> 5;
    const int e = t & 31;
    const int* dst = edge_index + EE;
    const int d = dst[s*DEG + e];
    float part = p_ws[d] * hv_ws[s*DEG + e];
    part += __shfl_xor(part, 1);
    part += __shfl_xor(part, 2);
    part += __shfl_xor(part, 4);
    part += __shfl_xor(part, 8);
    part += __shfl_xor(part, 16);
    if (e == 0) {
        float interf = part + VAR_F;
        out[s] = -log1pf(valid_ws[s] / interf) * 1.4426950408889634f;
    }
}

extern "C" void kernel_launch(void* const* d_in, const int* in_sizes, int n_in,
                              void* d_out, int out_size, void* d_ws, size_t ws_size,
                              hipStream_t stream) {
    const float* x         = (const float*)d_in[0];
    const float* edge_attr = (const float*)d_in[1];
    const float* H         = (const float*)d_in[2];
    const int*   edge_idx  = (const int*)  d_in[3];
    const float* Wm1 = (const float*)d_in[4];
    const float* bm1 = (const float*)d_in[5];
    const float* Wm2 = (const float*)d_in[6];
    const float* bm2 = (const float*)d_in[7];
    const float* Wu1 = (const float*)d_in[8];
    const float* bu1 = (const float*)d_in[9];
    const float* Wu2 = (const float*)d_in[10];
    const float* bu2 = (const float*)d_in[11];
    const float* Wh1 = (const float*)d_in[12];
    const float* bh1 = (const float*)d_in[13];
    const float* Wh2 = (const float*)d_in[14];
    const float* bh2 = (const float*)d_in[15];
    float* out = (float*)d_out;

    float* p_ws     = (float*)d_ws;            // KN
    float* valid_ws = p_ws + KN;               // KN
    float* hv_ws    = valid_ws + KN;           // KN*DEG

    mpnn_fused<<<KN, 64, 0, stream>>>(x, edge_attr, H, edge_idx,
                                      Wm1, bm1, Wm2, bm2,
                                      Wu1, bu1, Wu2, bu2, Wh1, bh1, Wh2, bh2,
                                      p_ws, valid_ws, hv_ws);
    mpnn_interf<<<(KN*DEG)/256, 256, 0, stream>>>(edge_idx, p_ws, valid_ws,
                                                  hv_ws, out);
}